// Round 6
// baseline (660.857 us; speedup 1.0000x reference)
//
#include <hip/hip_runtime.h>
#include <math.h>

#define B_  32
#define S_  2048
#define DV  1024
#define U_  1024

typedef __attribute__((ext_vector_type(8))) short bf16x8;
typedef __attribute__((ext_vector_type(4))) float f32x4;

__device__ inline unsigned short f2bf(float f) {
    unsigned int x = __float_as_uint(f);
    return (unsigned short)((x + 0x7fffu + ((x >> 16) & 1u)) >> 16);
}

__device__ inline uint4 pack8(float4 a, float4 b) {
    union { unsigned short s[8]; uint4 u; } p;
    p.s[0] = f2bf(a.x); p.s[1] = f2bf(a.y); p.s[2] = f2bf(a.z); p.s[3] = f2bf(a.w);
    p.s[4] = f2bf(b.x); p.s[5] = f2bf(b.y); p.s[6] = f2bf(b.z); p.s[7] = f2bf(b.w);
    return p.u;
}

__device__ inline float tanh_fast(float x) {
    float ax = fabsf(x);
    float e  = __expf(ax + ax);
    float t  = 1.0f - __fdividef(2.0f, e + 1.0f);
    return copysignf(t, x);
}

// async global->LDS, 16B per lane; LDS dest is the wave-uniform base.
__device__ __forceinline__ void gload16(const void* g, void* l) {
    __builtin_amdgcn_global_load_lds(
        (const __attribute__((address_space(1))) void*)g,
        (__attribute__((address_space(3))) void*)l,
        16, 0, 0);
}

#define ASM_VMCNT(N) asm volatile("s_waitcnt vmcnt(" #N ")" ::: "memory")
#define ASM_LGKM0()  do { asm volatile("s_waitcnt lgkmcnt(0)" ::: "memory"); \
                          __builtin_amdgcn_sched_barrier(0); } while (0)

// ---------------- prep_small: W1T | projq_full | zero scores | zero ctx -----
// block ranges (all independent):
//   [0,256)    prep_w1t  (W1 -> W1T bf16, 64x64 transpose tiles)
//   [256,384)  projq     (t[b,u] = b1[u]+b2[u]+q[b,:]@W2[:,u], no atomics)
//   [384,640)  zero scores (65536 floats)
//   [640,768)  zero ctx    (32768 floats)
__global__ __launch_bounds__(256)
void prep_small(const float* __restrict__ W1, unsigned short* __restrict__ W1T,
                const float* __restrict__ query, const float* __restrict__ W2,
                const float* __restrict__ b1, const float* __restrict__ b2,
                float* __restrict__ t, float* __restrict__ scores,
                float* __restrict__ ctx) {
    const int bid = blockIdx.x;
    const int tid = threadIdx.x;

    if (bid < 256) {
        __shared__ float tile[64][65];
        int k0 = (bid & 15) * 64, u0 = (bid >> 4) * 64;
        int lr = tid >> 4, lc = (tid & 15) * 4;
#pragma unroll
        for (int j = 0; j < 4; ++j) {
            float4 f = *(const float4*)&W1[(size_t)(k0 + lr + j * 16) * U_ + u0 + lc];
            tile[lr + j * 16][lc + 0] = f.x; tile[lr + j * 16][lc + 1] = f.y;
            tile[lr + j * 16][lc + 2] = f.z; tile[lr + j * 16][lc + 3] = f.w;
        }
        __syncthreads();
        int ur = tid >> 2, kq = (tid & 3) * 16;
        union { unsigned short s[8]; uint4 u; } p0, p1;
#pragma unroll
        for (int e = 0; e < 8; ++e) p0.s[e] = f2bf(tile[kq + e][ur]);
#pragma unroll
        for (int e = 0; e < 8; ++e) p1.s[e] = f2bf(tile[kq + 8 + e][ur]);
        unsigned short* dst = W1T + (size_t)(u0 + ur) * 1024 + k0 + kq;
        *(uint4*)dst       = p0.u;
        *(uint4*)(dst + 8) = p1.u;
    } else if (bid < 384) {
        __shared__ float qs2[1024];
        int i = bid - 256;
        int b = i >> 2, uq = i & 3;
        for (int j = tid; j < 1024; j += 256) qs2[j] = query[b * DV + j];
        __syncthreads();
        int u = uq * 256 + tid;
        float a0 = 0.f, a1 = 0.f, a2 = 0.f, a3 = 0.f;
        float a4 = 0.f, a5 = 0.f, a6 = 0.f, a7 = 0.f;
        const float* w = W2 + u;
        for (int k = 0; k < 1024; k += 8) {
            a0 += qs2[k + 0] * w[(size_t)(k + 0) * U_];
            a1 += qs2[k + 1] * w[(size_t)(k + 1) * U_];
            a2 += qs2[k + 2] * w[(size_t)(k + 2) * U_];
            a3 += qs2[k + 3] * w[(size_t)(k + 3) * U_];
            a4 += qs2[k + 4] * w[(size_t)(k + 4) * U_];
            a5 += qs2[k + 5] * w[(size_t)(k + 5) * U_];
            a6 += qs2[k + 6] * w[(size_t)(k + 6) * U_];
            a7 += qs2[k + 7] * w[(size_t)(k + 7) * U_];
        }
        t[b * U_ + u] = b1[u] + b2[u]
                      + ((a0 + a1) + (a2 + a3)) + ((a4 + a5) + (a6 + a7));
    } else if (bid < 640) {
        scores[(bid - 384) * 256 + tid] = 0.f;
    } else {
        ctx[(bid - 640) * 256 + tid] = 0.f;
    }
}

// ---------------- K2 v6: 256x256 tile, BK=64, 8-phase, fp32-A reg-staged ----
// No cvt pass: A read fp32 from row-major values (4x float4/thread, 64-B
// contiguous per 4 lanes), f2bf'd in-register (bit-identical to the old
// prepass image), ds_write'd with the XOR swizzle directly.  B path and the
// entire compute body (frag reads, MFMA order, epilogue) verbatim from R5.
//
// A-set ledger (sets s0/s1 ping-pong; 4 float4 each):
//   issue ph0: alpha=s0 (A1 of kt=2it+1)   write ph1 -> d1.A1 (81920)
//   issue ph3: beta =s1 (A0 of kt=2it+2)   write ph4 -> d0.A0 (0)      [pf]
//   issue ph4: gamma=s0 (A1 of kt=2it+2)   write ph5 -> d0.A1 (16384)  [pf]
//   issue ph7: delta=s1 (A0 of kt=2it+3)   write next-ph0 -> d1.A0 (65536) [pf]
// Write-after-read audit: each target region's last ds_read is >=1 barrier
// before the write (d1.A0 read prev ph4/ph6; d1.A1 read ph4-7 AFTER its ph1
// write of THIS iter's kt1; d0.A0 read ph0/ph2 < ph4; d0.A1 read ph0/ph2 < ph5).
// vmcnt ledger (issue order per iter: A4,B2,B2,A4,A4,B2,B2,A4):
//   ph0: +alpha -> 8,  vmcnt(4) retires delta    ; write delta
//   ph1: +B    -> 6,  vmcnt(2) retires alpha    ; write alpha
//   ph3-end:    8,  vmcnt(4) retires ph1/ph2 B (d1 complete)   [pf else 0]
//   ph4: +gamma-> 8,  vmcnt(4) retires beta     ; write beta
//   ph5: +B    -> 6,  vmcnt(2) retires gamma    ; write gamma
//   ph7-end:    8,  vmcnt(4) retires ph5/ph6 B (d0 complete)   [pf]
#define MFMA16(MB, NB)                                                          \
    _Pragma("unroll") for (int ks = 0; ks < 2; ++ks)                            \
    _Pragma("unroll") for (int n = 0; n < 2; ++n)                               \
    _Pragma("unroll") for (int m = 0; m < 4; ++m)                               \
        acc[(MB)+m][(NB)+n] = __builtin_amdgcn_mfma_f32_16x16x32_bf16(          \
            af[m][ks], bf[n][ks], acc[(MB)+m][(NB)+n], 0, 0, 0);

#define ISSUEA(Sa, Sb, Sc, Sd, kt, h) do {                                      \
    const float4* _s = (const float4*)(aRow + (size_t)(h) * 131072 + (kt) * 64);\
    Sa = _s[0]; Sb = _s[1]; Sc = _s[2]; Sd = _s[3]; } while (0)

#define WRITEA(Sa, Sb, Sc, Sd, dOff) do {                                       \
    *(uint4*)(lds + (dOff) + wO0) = pack8(Sa, Sb);                              \
    *(uint4*)(lds + (dOff) + wO1) = pack8(Sc, Sd); } while (0)

__launch_bounds__(512, 2)
__global__ void scores_mfma8f(const float* __restrict__ values,
                              const unsigned short* __restrict__ W1T,
                              const float* __restrict__ tvec,
                              const float* __restrict__ V,
                              float* __restrict__ scores) {
    __shared__ __align__(16) char lds[131072];   // 128 KB -> 1 block/CU

    const int tid  = threadIdx.x;
    const int lane = tid & 63;
    const int wave = tid >> 6;        // 0..7
    const int wm   = wave >> 2;       // 0..1  (row half of 256)
    const int wn   = wave & 3;        // 0..3  (64-col strip of 256)
    const int l15  = lane & 15;
    const int lq   = lane >> 4;       // 0..3

    const int id    = blockIdx.x;
    const int wg    = (id & 7) * 128 + (id >> 3);
    const int utile = wg & 3;                    // 4 u-tiles of 256
    const int stile = wg >> 2;                   // 256 s-tiles of 256
    const size_t row0 = (size_t)stile * 256;
    const int b       = (int)(row0 >> 11);
    const int s_local = (int)(row0 & 2047);
    const int u0      = utile * 256;

    // B staging: row-major W1T, inverse-XOR per-lane source (unchanged)
    const int rowst = wave * 8 + (lane >> 3);
    const int kch8  = ((lane & 7) ^ ((lane >> 3) & 7)) * 8;
    const unsigned short* bSrc = W1T + (size_t)(u0 + rowst) * 1024 + kch8;
    char* const dstW = lds + wave * 1024;

    // A reg-stage constants: thread covers (row rA, 16-k chunk kcA) of a half
    const int rA  = tid >> 2;          // 0..127
    const int kcA = tid & 3;           // 16-k chunk within 64-k tile
    const int c0  = (2 * kcA) ^ (rA & 7);
    const int wO0 = rA * 128 + c0 * 16;
    const int wO1 = rA * 128 + (c0 ^ 1) * 16;
    const float* aRow = values + (row0 + rA) * 1024 + kcA * 16;

    // fragment read lane offsets (bytes) — unchanged
    const int ao0 = wm * 16384 + l15 * 128 + ((lq ^ (l15 & 7)) << 4);
    const int ao1 = ao0 ^ 64;
    const int bo0 = 32768 + (wn >> 1) * 16384 + (wn & 1) * 8192
                  + l15 * 128 + ((lq ^ (l15 & 7)) << 4);
    const int bo1 = bo0 ^ 64;

    f32x4 acc[8][4];
#pragma unroll
    for (int m = 0; m < 8; ++m)
#pragma unroll
        for (int n = 0; n < 4; ++n) acc[m][n] = (f32x4)0.f;

    bf16x8 af[4][2];
    bf16x8 bf[2][2];

    auto stageB = [&](const unsigned short* s, int dOff) {
        gload16(s,             dstW + dOff);
        gload16(s + 64 * 1024, dstW + dOff + 8192);
    };
    auto readA4 = [&](int base) {
#pragma unroll
        for (int m = 0; m < 4; ++m) {
            af[m][0] = *(const bf16x8*)(lds + base + m * 2048 + ao0);
            af[m][1] = *(const bf16x8*)(lds + base + m * 2048 + ao1);
        }
    };
    auto readB2 = [&](int base) {
#pragma unroll
        for (int n = 0; n < 2; ++n) {
            bf[n][0] = *(const bf16x8*)(lds + base + n * 2048 + bo0);
            bf[n][1] = *(const bf16x8*)(lds + base + n * 2048 + bo1);
        }
    };

    float4 s0a, s0b, s0c, s0d;   // set 0
    float4 s1a, s1b, s1c, s1d;   // set 1
    float4 s2a, s2b, s2c, s2d;   // prologue-only extra set

    // ---- prologue: kt0 A (both halves, reg) + kt0 B (gload) + kt1.A0 (reg)
    ISSUEA(s0a, s0b, s0c, s0d, 0, 0);             // p0 -> d0.A0
    ISSUEA(s2a, s2b, s2c, s2d, 0, 1);             // p1 -> d0.A1
    stageB(bSrc,          32768);                 // d0.B0
    stageB(bSrc + 131072, 49152);                 // d0.B1
    ISSUEA(s1a, s1b, s1c, s1d, 1, 0);             // delta0 -> d1.A0 (write it0-ph0)
    ASM_VMCNT(8);                                 // retire p0,p1 (16 -> 8)
    WRITEA(s0a, s0b, s0c, s0d, 0);
    WRITEA(s2a, s2b, s2c, s2d, 16384);
    ASM_VMCNT(4);                                 // retire B (leave delta0)
    ASM_LGKM0();
    __builtin_amdgcn_s_barrier();
    __builtin_amdgcn_sched_barrier(0);

    for (int it = 0; it < 8; ++it) {
        const bool pf = (it < 7);
        // ---------- phase 0: d0, m0-3 x n0-1 ----------
        ISSUEA(s0a, s0b, s0c, s0d, 2 * it + 1, 1);   // alpha
        ASM_VMCNT(4);                                // delta landed
        WRITEA(s1a, s1b, s1c, s1d, 65536);           // delta -> d1.A0
        readA4(0);
        readB2(0);
        __builtin_amdgcn_s_barrier();
        ASM_LGKM0();
        __builtin_amdgcn_s_setprio(1);
        MFMA16(0, 0);
        __builtin_amdgcn_s_setprio(0);
        __builtin_amdgcn_s_barrier();
        // ---------- phase 1: d0, m0-3 x n2-3 ----------
        stageB(bSrc + 64, 98304);                    // d1.B0
        ASM_VMCNT(2);                                // alpha landed
        WRITEA(s0a, s0b, s0c, s0d, 81920);           // alpha -> d1.A1
        readB2(2 * 2048);
        __builtin_amdgcn_s_barrier();
        ASM_LGKM0();
        __builtin_amdgcn_s_setprio(1);
        MFMA16(0, 2);
        __builtin_amdgcn_s_setprio(0);
        __builtin_amdgcn_s_barrier();
        // ---------- phase 2: d0, m4-7 x n2-3 ----------
        stageB(bSrc + 64 + 131072, 114688);          // d1.B1
        readA4(4 * 2048);
        __builtin_amdgcn_s_barrier();
        ASM_LGKM0();
        __builtin_amdgcn_s_setprio(1);
        MFMA16(4, 2);
        __builtin_amdgcn_s_setprio(0);
        __builtin_amdgcn_s_barrier();
        // ---------- phase 3: d0, m4-7 x n0-1 ----------
        readB2(0);
        if (pf) ISSUEA(s1a, s1b, s1c, s1d, 2 * it + 2, 0);   // beta
        __builtin_amdgcn_s_barrier();
        ASM_LGKM0();
        __builtin_amdgcn_s_setprio(1);
        MFMA16(4, 0);
        __builtin_amdgcn_s_setprio(0);
        __builtin_amdgcn_sched_barrier(0);
        if (pf) { ASM_VMCNT(4); } else { ASM_VMCNT(0); }     // d1 B complete
        __builtin_amdgcn_s_barrier();
        __builtin_amdgcn_sched_barrier(0);
        // ---------- phase 4: d1, m0-3 x n0-1 ----------
        if (pf) {
            ISSUEA(s0a, s0b, s0c, s0d, 2 * it + 2, 1);       // gamma
            ASM_VMCNT(4);                                    // beta landed
            WRITEA(s1a, s1b, s1c, s1d, 0);                   // beta -> d0.A0
        }
        readA4(65536);
        readB2(65536);
        __builtin_amdgcn_s_barrier();
        ASM_LGKM0();
        __builtin_amdgcn_s_setprio(1);
        MFMA16(0, 0);
        __builtin_amdgcn_s_setprio(0);
        __builtin_amdgcn_s_barrier();
        // ---------- phase 5: d1, m0-3 x n2-3 ----------
        readB2(65536 + 2 * 2048);
        if (pf) {
            stageB(bSrc + 128, 32768);                       // d0.B0
            ASM_VMCNT(2);                                    // gamma landed
            WRITEA(s0a, s0b, s0c, s0d, 16384);               // gamma -> d0.A1
        }
        __builtin_amdgcn_s_barrier();
        ASM_LGKM0();
        __builtin_amdgcn_s_setprio(1);
        MFMA16(0, 2);
        __builtin_amdgcn_s_setprio(0);
        __builtin_amdgcn_s_barrier();
        // ---------- phase 6: d1, m4-7 x n2-3 ----------
        if (pf) stageB(bSrc + 128 + 131072, 49152);          // d0.B1
        readA4(65536 + 4 * 2048);
        __builtin_amdgcn_s_barrier();
        ASM_LGKM0();
        __builtin_amdgcn_s_setprio(1);
        MFMA16(4, 2);
        __builtin_amdgcn_s_setprio(0);
        __builtin_amdgcn_s_barrier();
        // ---------- phase 7: d1, m4-7 x n0-1 ----------
        readB2(65536);
        if (pf) ISSUEA(s1a, s1b, s1c, s1d, 2 * it + 3, 0);   // delta
        __builtin_amdgcn_s_barrier();
        ASM_LGKM0();
        __builtin_amdgcn_s_setprio(1);
        MFMA16(4, 0);
        __builtin_amdgcn_s_setprio(0);
        __builtin_amdgcn_sched_barrier(0);
        if (pf) { ASM_VMCNT(4); }                            // d0 B complete
        __builtin_amdgcn_s_barrier();
        __builtin_amdgcn_sched_barrier(0);

        bSrc += 128;
    }

    // epilogue: score[row] += sum_u tanh(P + t[b,u]) * V[u]
    __syncthreads();
    float* fscore = (float*)lds;
    if (tid < 256) fscore[tid] = 0.f;
    __syncthreads();
    float tu[4], vu[4];
#pragma unroll
    for (int n = 0; n < 4; ++n) {
        int u = u0 + wn * 64 + n * 16 + l15;
        tu[n] = tvec[b * U_ + u];
        vu[n] = V[u];
    }
#pragma unroll
    for (int m = 0; m < 8; ++m) {
#pragma unroll
        for (int r = 0; r < 4; ++r) {
            float p = 0.f;
#pragma unroll
            for (int n = 0; n < 4; ++n) p += tanh_fast(acc[m][n][r] + tu[n]) * vu[n];
            p += __shfl_xor(p, 1);
            p += __shfl_xor(p, 2);
            p += __shfl_xor(p, 4);
            p += __shfl_xor(p, 8);
            if (l15 == 0) atomicAdd(&fscore[wm * 128 + m * 16 + lq * 4 + r], p);
        }
    }
    __syncthreads();
    if (tid < 256) atomicAdd(&scores[(size_t)b * S_ + s_local + tid], fscore[tid]);
}

// ---------------- FUSED softmax + context (unchanged from R5) ---------------
__global__ __launch_bounds__(256)
void fused_sm_ctx(const float* __restrict__ scores, const float* __restrict__ values,
                  float* __restrict__ wout, float* __restrict__ ctx) {
    const int b   = blockIdx.x;     // 32
    const int sc  = blockIdx.y;     // 16 chunks of 128 s
    const int tid = threadIdx.x;    // 256
    __shared__ float red[256];
    __shared__ float ws_[128];

    float v[8];
    float m = -1e30f;
#pragma unroll
    for (int i = 0; i < 8; ++i) {
        v[i] = scores[(size_t)b * S_ + tid + i * 256];
        m = fmaxf(m, v[i]);
    }
    red[tid] = m; __syncthreads();
    for (int off = 128; off > 0; off >>= 1) {
        if (tid < off) red[tid] = fmaxf(red[tid], red[tid + off]);
        __syncthreads();
    }
    m = red[0];
    __syncthreads();
    float s = 0.f;
#pragma unroll
    for (int i = 0; i < 8; ++i) s += __expf(v[i] - m);
    red[tid] = s; __syncthreads();
    for (int off = 128; off > 0; off >>= 1) {
        if (tid < off) red[tid] += red[tid + off];
        __syncthreads();
    }
    float inv = 1.f / red[0];
    __syncthreads();

    if (tid < 128) {
        float x = scores[(size_t)b * S_ + sc * 128 + tid];
        float w = __expf(x - m) * inv;
        ws_[tid] = w;
        wout[(size_t)b * S_ + sc * 128 + tid] = w;
    }
    __syncthreads();

    const float4* vp = (const float4*)(values + ((size_t)b * S_ + sc * 128) * DV) + tid;
    float ax = 0.f, ay = 0.f, az = 0.f, aw = 0.f;
#pragma unroll 4
    for (int s2 = 0; s2 < 128; ++s2) {
        float4 vv = vp[(size_t)s2 * 256];
        float wv = ws_[s2];
        ax += wv * vv.x; ay += wv * vv.y; az += wv * vv.z; aw += wv * vv.w;
    }
    float* c = ctx + b * DV + tid * 4;
    atomicAdd(c + 0, ax); atomicAdd(c + 1, ay);
    atomicAdd(c + 2, az); atomicAdd(c + 3, aw);
}

// ================= legacy kernels (low ws fallback path) ====================
__global__ void init_kernel(const float* __restrict__ b1, const float* __restrict__ b2,
                            float* __restrict__ t, float* __restrict__ ctx,
                            float* __restrict__ scores) {
    int i = blockIdx.x * 256 + threadIdx.x;   // 65536
    scores[i] = 0.f;
    if (i < B_ * U_) {
        int u = i & (U_ - 1);
        t[i]   = b1[u] + b2[u];
        ctx[i] = 0.f;
    }
}

__global__ void projq_kernel(const float* __restrict__ q, const float* __restrict__ W2,
                             float* __restrict__ t) {
    int b  = blockIdx.x;
    int ks = blockIdx.y;
    int tid = threadIdx.x;
    __shared__ float qs[64];
    if (tid < 64) qs[tid] = q[b * DV + ks * 64 + tid];
    __syncthreads();
    float a0 = 0.f, a1 = 0.f, a2 = 0.f, a3 = 0.f;
    const float* w = W2 + (size_t)(ks * 64) * U_;
    for (int d = 0; d < 64; ++d) {
        float qd = qs[d];
        const float* wr = w + (size_t)d * U_ + tid;
        a0 += qd * wr[0];
        a1 += qd * wr[256];
        a2 += qd * wr[512];
        a3 += qd * wr[768];
    }
    atomicAdd(&t[b * U_ + tid      ], a0);
    atomicAdd(&t[b * U_ + tid + 256], a1);
    atomicAdd(&t[b * U_ + tid + 512], a2);
    atomicAdd(&t[b * U_ + tid + 768], a3);
}

__launch_bounds__(256, 2)
__global__ void scores_vec(const float* __restrict__ values, const float* __restrict__ W1,
                           const float* __restrict__ t, const float* __restrict__ V,
                           float* __restrict__ scores) {
    __shared__ float vA[16][132];
    __shared__ float vB[16][68];
    __shared__ float fscore[128];
    const int b   = blockIdx.y;
    const int s0  = blockIdx.x * 128;
    const int tid = threadIdx.x;
    const int tx  = tid & 15, ty = tid >> 4;
    if (tid < 128) fscore[tid] = 0.f;
    const float* vbase = values + ((size_t)b * S_ + s0) * (size_t)DV;
    const int lm = tid >> 2, lkq = (tid & 3) * 4;
    const int lbk = tid >> 4, lbj = (tid & 15) * 4;
    for (int nt = 0; nt < U_ / 64; ++nt) {
        const int u0 = nt * 64;
        float acc[8][4];
#pragma unroll
        for (int i = 0; i < 8; ++i)
#pragma unroll
            for (int j = 0; j < 4; ++j) acc[i][j] = 0.f;
        for (int k0 = 0; k0 < DV; k0 += 16) {
            __syncthreads();
            const float4 v0 = *(const float4*)(vbase + (size_t)lm * DV + k0 + lkq);
            const float4 v1 = *(const float4*)(vbase + (size_t)(lm + 64) * DV + k0 + lkq);
            vA[lkq + 0][lm] = v0.x; vA[lkq + 1][lm] = v0.y;
            vA[lkq + 2][lm] = v0.z; vA[lkq + 3][lm] = v0.w;
            vA[lkq + 0][lm + 64] = v1.x; vA[lkq + 1][lm + 64] = v1.y;
            vA[lkq + 2][lm + 64] = v1.z; vA[lkq + 3][lm + 64] = v1.w;
            *(float4*)&vB[lbk][lbj] = *(const float4*)(W1 + (size_t)(k0 + lbk) * U_ + u0 + lbj);
            __syncthreads();
#pragma unroll
            for (int k = 0; k < 16; ++k) {
                float4 va0 = *(const float4*)&vA[k][ty * 8];
                float4 va1 = *(const float4*)&vA[k][ty * 8 + 4];
                float4 vb  = *(const float4*)&vB[k][tx * 4];
                float a_[8] = {va0.x, va0.y, va0.z, va0.w, va1.x, va1.y, va1.z, va1.w};
                float b_[4] = {vb.x, vb.y, vb.z, vb.w};
#pragma unroll
                for (int i = 0; i < 8; ++i)
#pragma unroll
                    for (int j = 0; j < 4; ++j) acc[i][j] += a_[i] * b_[j];
            }
        }
        float tq[4], vv[4];
#pragma unroll
        for (int j = 0; j < 4; ++j) {
            int u = u0 + tx * 4 + j;
            tq[j] = t[b * U_ + u];
            vv[j] = V[u];
        }
#pragma unroll
        for (int i = 0; i < 8; ++i) {
            float p = 0.f;
#pragma unroll
            for (int j = 0; j < 4; ++j) p += tanhf(acc[i][j] + tq[j]) * vv[j];
            p += __shfl_down(p, 8, 16);
            p += __shfl_down(p, 4, 16);
            p += __shfl_down(p, 2, 16);
            p += __shfl_down(p, 1, 16);
            if (tx == 0) fscore[ty * 8 + i] += p;
        }
    }
    __syncthreads();
    if (tid < 128) scores[(size_t)b * S_ + s0 + tid] = fscore[tid];
}

__global__ void softmax_kernel(const float* __restrict__ scores, float* __restrict__ wout) {
    int b = blockIdx.x;
    int tid = threadIdx.x;
    __shared__ float red[256];
    float v[8];
    float m = -1e30f;
#pragma unroll
    for (int i = 0; i < 8; ++i) {
        v[i] = scores[(size_t)b * S_ + tid + i * 256];
        m = fmaxf(m, v[i]);
    }
    red[tid] = m; __syncthreads();
    for (int off = 128; off > 0; off >>= 1) {
        if (tid < off) red[tid] = fmaxf(red[tid], red[tid + off]);
        __syncthreads();
    }
    m = red[0];
    __syncthreads();
    float s = 0.f;
#pragma unroll
    for (int i = 0; i < 8; ++i) { v[i] = __expf(v[i] - m); s += v[i]; }
    red[tid] = s; __syncthreads();
    for (int off = 128; off > 0; off >>= 1) {
        if (tid < off) red[tid] += red[tid + off];
        __syncthreads();
    }
    float inv = 1.f / red[0];
#pragma unroll
    for (int i = 0; i < 8; ++i) wout[(size_t)b * S_ + tid + i * 256] = v[i] * inv;
}

__global__ void context_kernel(const float* __restrict__ values, const float* __restrict__ w,
                               float* __restrict__ ctx) {
    int b   = blockIdx.x;
    int sc  = blockIdx.y;
    int tid = threadIdx.x;
    __shared__ float ws_[128];
    if (tid < 128) ws_[tid] = w[(size_t)b * S_ + sc * 128 + tid];
    __syncthreads();
    const float4* vp = (const float4*)(values + ((size_t)b * S_ + sc * 128) * DV) + tid;
    float ax = 0.f, ay = 0.f, az = 0.f, aw = 0.f;
#pragma unroll 4
    for (int s = 0; s < 128; ++s) {
        float4 v = vp[(size_t)s * 256];
        float wv = ws_[s];
        ax += wv * v.x; ay += wv * v.y; az += wv * v.z; aw += wv * v.w;
    }
    float* c = ctx + b * DV + tid * 4;
    atomicAdd(c + 0, ax); atomicAdd(c + 1, ay);
    atomicAdd(c + 2, az); atomicAdd(c + 3, aw);
}

// ---------------- launch ----------------------------------------------------
extern "C" void kernel_launch(void* const* d_in, const int* in_sizes, int n_in,
                              void* d_out, int out_size, void* d_ws, size_t ws_size,
                              hipStream_t stream) {
    const float* query  = (const float*)d_in[0];
    const float* values = (const float*)d_in[1];
    const float* W1     = (const float*)d_in[2];
    const float* b1     = (const float*)d_in[3];
    const float* W2     = (const float*)d_in[4];
    const float* b2     = (const float*)d_in[5];
    const float* V      = (const float*)d_in[6];
    // bV (d_in[7]) shifts all scores equally -> softmax-invariant.

    float* out  = (float*)d_out;
    float* ctx  = out;                 // [32, 1024]
    float* wout = out + B_ * DV;       // [32, 2048]

    char* ws = (char*)d_ws;
    const size_t W1T_BYTES = (size_t)U_ * DV * 2;              // 2 MB
    const size_t T_BYTES   = (size_t)B_ * U_ * 4;              // 128 KB
    const size_t SC_BYTES  = (size_t)B_ * S_ * 4;              // 256 KB

    if (ws_size >= W1T_BYTES + T_BYTES + SC_BYTES) {
        // fast path: 3 launches, no cvt pass (fp32 A staged in-kernel)
        unsigned short* W1T = (unsigned short*)ws;
        float* t      = (float*)(ws + W1T_BYTES);
        float* scores = t + B_ * U_;

        prep_small   <<<dim3(768),    256, 0, stream>>>(W1, W1T, query, W2,
                                                        b1, b2, t, scores, ctx);
        scores_mfma8f<<<dim3(1024),   512, 0, stream>>>(values, W1T, t, V, scores);
        fused_sm_ctx <<<dim3(32, 16), 256, 0, stream>>>(scores, values, wout, ctx);
    } else {
        // low path: round-1 fp32 vector kernel (384 KB ws, proven)
        float* t      = (float*)ws;
        float* scores = t + B_ * U_;

        init_kernel   <<<dim3(256),      256, 0, stream>>>(b1, b2, t, ctx, scores);
        projq_kernel  <<<dim3(32, 16),   256, 0, stream>>>(query, W2, t);
        scores_vec    <<<dim3(16, 32),   256, 0, stream>>>(values, W1, t, V, scores);
        softmax_kernel<<<dim3(32),       256, 0, stream>>>(scores, wout);
        context_kernel<<<dim3(32, 16),   256, 0, stream>>>(values, wout, ctx);
    }
}